// Round 7
// baseline (948.734 us; speedup 1.0000x reference)
//
#include <hip/hip_runtime.h>
#include <hip/hip_bf16.h>

// DynamicRouterMoE: N=8192 tokens, C=1024, Hdim=4096, E=16, top-2.
// R7: reg-staged T14 staging (global->VGPR->ds_write_b128) replacing
//     global_load_lds in both 256x256 8-wave GEMMs. 1 barrier per K-tile,
//     loads lead consumption by 2 phases (compiler-counted vmcnt), swizzle
//     applied at the ds_write address (same involution as R6's read side).

typedef __attribute__((ext_vector_type(4))) float f32x4;
typedef __attribute__((ext_vector_type(8))) __bf16 bf16x8;
typedef __attribute__((ext_vector_type(8))) unsigned short u16x8;

#define NEXP 16
#define CAP  2048
#define CDIM 1024
#define HDIM 4096
#define KS2 2            // split-K factor for gemm2
#define BMG 256          // GEMM tile M
#define BNG 256          // GEMM tile N
#define SLOT 8192        // elems per LDS slot: 256 rows x 32 k

__device__ __forceinline__ unsigned short f2bf(float f) {
  return __builtin_bit_cast(unsigned short, (__bf16)f);
}

// Bijective XCD swizzle (requires nwg % 8 == 0; true for all GEMM grids).
__device__ __forceinline__ void xcd_remap(int& bx, int& by, int& bz) {
  const int gx = gridDim.x, gy = gridDim.y;
  const int nwg = gx * gy * gridDim.z;
  int flat = blockIdx.x + gx * (blockIdx.y + gy * blockIdx.z);
  flat = (flat & 7) * (nwg >> 3) + (flat >> 3);
  bx = flat % gx;
  const int t = flat / gx;
  by = t % gy;
  bz = t / gy;
}

// ---------------- router: logits(fp64) -> top2 -> softmax -> lists ----------
__global__ __launch_bounds__(64) void router_kernel(
    const float* __restrict__ x, const float* __restrict__ wr,
    float* __restrict__ pair_w, int* __restrict__ counts,
    int* __restrict__ lists)
{
  const int n = blockIdx.x;
  const int l = threadIdx.x;
  const float* xrow = x + (size_t)n * CDIM;
  double acc[NEXP];
#pragma unroll
  for (int e = 0; e < NEXP; e++) acc[e] = 0.0;
  for (int it = 0; it < CDIM / 64; it++) {
    const int c = l + it * 64;
    const double xv = (double)xrow[c];
    const float* w = wr + c * NEXP;
#pragma unroll
    for (int e = 0; e < NEXP; e++) acc[e] += xv * (double)w[e];
  }
#pragma unroll
  for (int e = 0; e < NEXP; e++) {
    double v = acc[e];
    for (int off = 32; off > 0; off >>= 1) v += __shfl_xor(v, off, 64);
    acc[e] = v;
  }
  if (l == 0) {
    int e0 = 0; double b0 = acc[0];
    for (int e = 1; e < NEXP; e++) if (acc[e] > b0) { b0 = acc[e]; e0 = e; }
    int e1 = -1; double b1v = -1e300;
    for (int e = 0; e < NEXP; e++) {
      if (e == e0) continue;
      if (acc[e] > b1v) { b1v = acc[e]; e1 = e; }
    }
    const double d = exp(b1v - b0);
    pair_w[2 * n]     = (float)(1.0 / (1.0 + d));
    pair_w[2 * n + 1] = (float)(d / (1.0 + d));
    int p0 = atomicAdd(&counts[e0], 1);
    if (p0 < CAP) lists[e0 * CAP + p0] = 2 * n;
    int p1 = atomicAdd(&counts[e1], 1);
    if (p1 < CAP) lists[e1 * CAP + p1] = 2 * n + 1;
  }
}

// ---------------- convert x -> bf16 ----------------------------------------
__global__ __launch_bounds__(256) void cvt_x_kernel(
    const float* __restrict__ x, unsigned short* __restrict__ xb, int n8)
{
  const int i = blockIdx.x * 256 + threadIdx.x;
  if (i >= n8) return;
  float4 a = ((const float4*)x)[2 * i];
  float4 b = ((const float4*)x)[2 * i + 1];
  u16x8 v;
  v[0] = f2bf(a.x); v[1] = f2bf(a.y); v[2] = f2bf(a.z); v[3] = f2bf(a.w);
  v[4] = f2bf(b.x); v[5] = f2bf(b.y); v[6] = f2bf(b.z); v[7] = f2bf(b.w);
  ((u16x8*)xb)[i] = v;
}

// ------------- transpose+convert: src fp32 [K][Nn] -> dst bf16 [Nn][K] ------
__global__ __launch_bounds__(256) void transpose_cvt_kernel(
    const float* __restrict__ src, unsigned short* __restrict__ dst,
    int K, int Nn)
{
  __shared__ __align__(16) unsigned short tile[64][72];  // +8 pad
  const size_t eoff = (size_t)blockIdx.z * K * Nn;
  const float* S = src + eoff;
  unsigned short* D = dst + eoff;
  const int n0 = blockIdx.x * 64, k0 = blockIdx.y * 64;
  const int t = threadIdx.x;
  {
    const int nl = (t & 15) * 4, kr = t >> 4;
#pragma unroll
    for (int p = 0; p < 4; p++) {
      const int k = kr + p * 16;
      float4 v = *(const float4*)(S + (size_t)(k0 + k) * Nn + n0 + nl);
      tile[nl + 0][k] = f2bf(v.x);
      tile[nl + 1][k] = f2bf(v.y);
      tile[nl + 2][k] = f2bf(v.z);
      tile[nl + 3][k] = f2bf(v.w);
    }
  }
  __syncthreads();
  {
    const int kq = (t & 7) * 8, nr = t >> 3;
#pragma unroll
    for (int p = 0; p < 2; p++) {
      const int n = nr + p * 32;
      u16x8 v = *(const u16x8*)&tile[n][kq];
      *(u16x8*)(D + (size_t)(n0 + n) * K + k0 + kq) = v;
    }
  }
}

// ========= 8-wave 256x256 reg-staged phase-split GEMM bodies ================
// LDS: A slots [par][h][256 rows][32 k] then B slots (8 x 16KB = 128KB).
// Stored quad position q' holds global quad g = q' ^ ((row>>1)&3).
// Staging: per thread rows sr0/sr1, global quad lane&3; ds_write to
// q' = (lane&3) ^ ((lane>>3)&3) (== (sr>>1)&3 involution). Loads for tile
// t+2 issue in phase t; ds_write of tile t+1 regs in phase t; compute tile t.

#define LOADR(ra0, ra1, rb0, rb1, koffb)                                       \
  do {                                                                         \
    ra0 = *(const u16x8*)(ag0 + (koffb));                                      \
    ra1 = *(const u16x8*)(ag1 + (koffb));                                      \
    rb0 = *(const u16x8*)(bg0 + (koffb));                                      \
    rb1 = *(const u16x8*)(bg1 + (koffb));                                      \
  } while (0)

#define DSW(parx, hx, ra0, ra1, rb0, rb1)                                      \
  do {                                                                         \
    unsigned short* SA_ = &lds[((parx) * 2 + (hx)) * SLOT];                    \
    unsigned short* SB_ = &lds[4 * SLOT + ((parx) * 2 + (hx)) * SLOT];         \
    *(u16x8*)(SA_ + sw0) = ra0;                                                \
    *(u16x8*)(SA_ + sw1) = ra1;                                                \
    *(u16x8*)(SB_ + sw0) = rb0;                                                \
    *(u16x8*)(SB_ + sw1) = rb1;                                                \
  } while (0)

#define COMPUTE(parx, hx)                                                      \
  do {                                                                         \
    const unsigned short* As_ = &lds[((parx) * 2 + (hx)) * SLOT];              \
    const unsigned short* Bs_ = &lds[4 * SLOT + ((parx) * 2 + (hx)) * SLOT];   \
    bf16x8 af[8], bfv[4];                                                      \
    _Pragma("unroll")                                                          \
    for (int mf = 0; mf < 8; mf++)                                             \
      af[mf] = *(const bf16x8*)(As_ + (wr * 128 + mf * 16 + lrow) * 32 + qsw); \
    _Pragma("unroll")                                                          \
    for (int nf = 0; nf < 4; nf++)                                             \
      bfv[nf] = *(const bf16x8*)(Bs_ + (wc * 64 + nf * 16 + lrow) * 32 + qsw); \
    __builtin_amdgcn_s_setprio(1);                                             \
    _Pragma("unroll")                                                          \
    for (int mf = 0; mf < 8; mf++)                                             \
      _Pragma("unroll")                                                        \
      for (int nf = 0; nf < 4; nf++)                                           \
        acc[mf][nf] = __builtin_amdgcn_mfma_f32_16x16x32_bf16(                 \
            af[mf], bfv[nf], acc[mf][nf], 0, 0, 0);                            \
    __builtin_amdgcn_s_setprio(0);                                             \
  } while (0)

#define SBAR asm volatile("s_barrier" ::: "memory")

#define GEMM_MAIN_LOOP(NT)                                                     \
  u16x8 eA0, eA1, eB0, eB1, oA0, oA1, oB0, oB1;                                \
  LOADR(eA0, eA1, eB0, eB1, 0);                                                \
  LOADR(oA0, oA1, oB0, oB1, 64);                                               \
  DSW(0, 0, eA0, eA1, eB0, eB1);                                               \
  DSW(0, 1, oA0, oA1, oB0, oB1);                                               \
  LOADR(eA0, eA1, eB0, eB1, 128);                                              \
  LOADR(oA0, oA1, oB0, oB1, 192);                                              \
  asm volatile("s_waitcnt lgkmcnt(0)" ::: "memory");                           \
  for (int tt = 0; tt < (NT); ++tt) {                                          \
    const int par = tt & 1;                                                    \
    SBAR;                                                                      \
    if (tt + 1 < (NT)) DSW(par ^ 1, 0, eA0, eA1, eB0, eB1);                    \
    if (tt + 2 < (NT)) LOADR(eA0, eA1, eB0, eB1, (tt + 2) * 128);              \
    COMPUTE(par, 0);                                                           \
    if (tt + 1 < (NT)) DSW(par ^ 1, 1, oA0, oA1, oB0, oB1);                    \
    if (tt + 2 < (NT)) LOADR(oA0, oA1, oB0, oB1, (tt + 2) * 128 + 64);         \
    COMPUTE(par, 1);                                                           \
  }

// ---------------- GEMM1: H[pair] = relu(xb[token] @ w1b[e]^T + b1[e]) -------
__global__ __launch_bounds__(512, 2) void gemm1_8p_kernel(
    const unsigned short* __restrict__ xb, const unsigned short* __restrict__ wb,
    const float* __restrict__ b1, const int* __restrict__ counts,
    const int* __restrict__ lists, unsigned short* __restrict__ Hb)
{
  int bx, by, bz;
  xcd_remap(bx, by, bz);
  const int e = bz;
  int cnt = counts[e]; if (cnt > CAP) cnt = CAP;
  const int m0 = by * BMG;
  if (m0 >= cnt) return;
  const int n0 = bx * BNG;
  const int* list = lists + e * CAP;
  const unsigned short* W = wb + (size_t)e * CDIM * HDIM;

  __shared__ __align__(16) unsigned short lds[8 * SLOT];  // 128 KB

  const int t = threadIdx.x, w = t >> 6, lane = t & 63;
  const int wr = w >> 2, wc = w & 3;          // 2M x 4N waves, each 128x64
  const int lrow = lane & 15, lgrp = lane >> 4;
  const int qsw = (lgrp ^ ((lrow >> 1) & 3)) * 8;   // read-side quad select

  // staging geometry
  const int sr0 = w * 16 + (lane >> 2), sr1 = 128 + sr0;
  const int wq = ((lane & 3) ^ ((lane >> 3) & 3)) * 8;  // write-side quad (elems)
  const int sw0 = sr0 * 32 + wq, sw1 = sr1 * 32 + wq;
  int ai0 = m0 + sr0; if (ai0 > cnt - 1) ai0 = cnt - 1;
  int ai1 = m0 + sr1; if (ai1 > cnt - 1) ai1 = cnt - 1;
  const char* ag0 = (const char*)(xb + (size_t)(list[ai0] >> 1) * CDIM) + (lane & 3) * 16;
  const char* ag1 = (const char*)(xb + (size_t)(list[ai1] >> 1) * CDIM) + (lane & 3) * 16;
  const char* bg0 = (const char*)(W + (size_t)(n0 + sr0) * CDIM) + (lane & 3) * 16;
  const char* bg1 = (const char*)(W + (size_t)(n0 + sr1) * CDIM) + (lane & 3) * 16;

  f32x4 acc[8][4] = {};

  GEMM_MAIN_LOOP(CDIM / 64)

  // epilogue: +b1, relu, bf16 scatter to Hb rows = pair ids
  int hrow[8][4]; bool valid[8][4];
#pragma unroll
  for (int mf = 0; mf < 8; mf++)
#pragma unroll
    for (int rr = 0; rr < 4; rr++) {
      const int mi = m0 + wr * 128 + mf * 16 + lgrp * 4 + rr;
      valid[mf][rr] = (mi < cnt);
      hrow[mf][rr] = list[valid[mf][rr] ? mi : (cnt - 1)];
    }
#pragma unroll
  for (int nf = 0; nf < 4; nf++) {
    const int col = n0 + wc * 64 + nf * 16 + lrow;
    const float bias = b1[e * HDIM + col];
#pragma unroll
    for (int mf = 0; mf < 8; mf++)
#pragma unroll
      for (int rr = 0; rr < 4; rr++)
        if (valid[mf][rr]) {
          float h = acc[mf][nf][rr] + bias;
          h = h > 0.f ? h : 0.f;
          Hb[(size_t)hrow[mf][rr] * HDIM + col] = f2bf(h);
        }
  }
}

// ---------------- GEMM2: out[token] += w_pair*(Hb[pair] @ w2b[e]^T + b2) ----
__global__ __launch_bounds__(512, 2) void gemm2_8p_kernel(
    const unsigned short* __restrict__ Hb, const unsigned short* __restrict__ wb,
    const float* __restrict__ b2, const float* __restrict__ pair_w,
    const int* __restrict__ counts, const int* __restrict__ lists,
    float* __restrict__ out)
{
  int bx, by, bz;
  xcd_remap(bx, by, bz);
  const int e = bz / KS2, ks = bz % KS2;
  int cnt = counts[e]; if (cnt > CAP) cnt = CAP;
  const int m0 = by * BMG;
  if (m0 >= cnt) return;
  const int n0 = bx * BNG;
  const int* list = lists + e * CAP;
  const unsigned short* W = wb + (size_t)e * HDIM * CDIM;
  const int kbegb = ks * (HDIM / KS2) * 2;  // byte offset of K chunk

  __shared__ __align__(16) unsigned short lds[8 * SLOT];  // 128 KB

  const int t = threadIdx.x, w = t >> 6, lane = t & 63;
  const int wr = w >> 2, wc = w & 3;
  const int lrow = lane & 15, lgrp = lane >> 4;
  const int qsw = (lgrp ^ ((lrow >> 1) & 3)) * 8;

  const int sr0 = w * 16 + (lane >> 2), sr1 = 128 + sr0;
  const int wq = ((lane & 3) ^ ((lane >> 3) & 3)) * 8;
  const int sw0 = sr0 * 32 + wq, sw1 = sr1 * 32 + wq;
  int ai0 = m0 + sr0; if (ai0 > cnt - 1) ai0 = cnt - 1;
  int ai1 = m0 + sr1; if (ai1 > cnt - 1) ai1 = cnt - 1;
  const char* ag0 = (const char*)(Hb + (size_t)list[ai0] * HDIM) + kbegb + (lane & 3) * 16;
  const char* ag1 = (const char*)(Hb + (size_t)list[ai1] * HDIM) + kbegb + (lane & 3) * 16;
  const char* bg0 = (const char*)(W + (size_t)(n0 + sr0) * HDIM) + kbegb + (lane & 3) * 16;
  const char* bg1 = (const char*)(W + (size_t)(n0 + sr1) * HDIM) + kbegb + (lane & 3) * 16;

  f32x4 acc[8][4] = {};

  GEMM_MAIN_LOOP((HDIM / KS2) / 64)

  // epilogue: +b2 (ks==0 only), scale by routing weight, atomic accumulate.
  float wgt[8][4]; int tok[8][4]; bool valid[8][4];
#pragma unroll
  for (int mf = 0; mf < 8; mf++)
#pragma unroll
    for (int rr = 0; rr < 4; rr++) {
      const int mi = m0 + wr * 128 + mf * 16 + lgrp * 4 + rr;
      valid[mf][rr] = (mi < cnt);
      const int p = list[valid[mf][rr] ? mi : (cnt - 1)];
      wgt[mf][rr] = pair_w[p];
      tok[mf][rr] = p >> 1;
    }
#pragma unroll
  for (int nf = 0; nf < 4; nf++) {
    const int col = n0 + wc * 64 + nf * 16 + lrow;
    const float bias = (ks == 0) ? b2[e * CDIM + col] : 0.f;
#pragma unroll
    for (int mf = 0; mf < 8; mf++)
#pragma unroll
      for (int rr = 0; rr < 4; rr++)
        if (valid[mf][rr])
          atomicAdd(out + (size_t)tok[mf][rr] * CDIM + col,
                    wgt[mf][rr] * (acc[mf][nf][rr] + bias));
  }
}

// ================= fallback kernels (fp32 inputs, reg-staged, 128²) =========
__device__ __forceinline__ int swz(int row, int b) {
  return row * 128 + (b ^ (((row >> 1) & 7) << 4));
}

#define MFMA_COMPUTE_F(Abase, Bbase)                                           \
  _Pragma("unroll")                                                            \
  for (int kk = 0; kk < 2; kk++) {                                             \
    bf16x8 af[4], bfr[4];                                                      \
    const int kb = (kk * 32 + lgrp * 8) * 2;                                   \
    _Pragma("unroll")                                                          \
    for (int i = 0; i < 4; i++)                                                \
      af[i] = *(const bf16x8*)((Abase) + swz(wm + i * 16 + lrow, kb));         \
    _Pragma("unroll")                                                          \
    for (int j = 0; j < 4; j++)                                                \
      bfr[j] = *(const bf16x8*)((Bbase) + swz(wn + j * 16 + lrow, kb));        \
    _Pragma("unroll")                                                          \
    for (int i = 0; i < 4; i++)                                                \
      _Pragma("unroll")                                                        \
      for (int j = 0; j < 4; j++)                                              \
        acc[i][j] = __builtin_amdgcn_mfma_f32_16x16x32_bf16(                   \
            af[i], bfr[j], acc[i][j], 0, 0, 0);                                \
  }

__global__ __launch_bounds__(256) void gemm1_f32_kernel(
    const float* __restrict__ x, const float* __restrict__ w1,
    const float* __restrict__ b1, const int* __restrict__ counts,
    const int* __restrict__ lists, unsigned short* __restrict__ Hb,
    int e_base, int h_by_pair)
{
  const int e = e_base + blockIdx.z;
  int cnt = counts[e]; if (cnt > CAP) cnt = CAP;
  const int m0 = blockIdx.y * 128;
  if (m0 >= cnt) return;
  const int n0 = blockIdx.x * 128;
  const int* list = lists + e * CAP;
  const float* W = w1 + (size_t)e * CDIM * HDIM;
  __shared__ __align__(16) unsigned short As[128 * 64];
  __shared__ __align__(16) unsigned short Bs[128 * 64];
  const int t = threadIdx.x;
  const int a_row = t >> 1, a_half = t & 1;
  int a_idx = m0 + a_row; if (a_idx > cnt - 1) a_idx = cnt - 1;
  const float* a_src = x + (size_t)(list[a_idx] >> 1) * CDIM + a_half * 32;
  const int b_np = t & 63, b_kg = t >> 6;
  const int wid = t >> 6, lane = t & 63;
  const int wm = (wid >> 1) * 64, wn = (wid & 1) * 64;
  const int lrow = lane & 15, lgrp = lane >> 4;
  f32x4 acc[4][4] = {};
  for (int kt = 0; kt < CDIM; kt += 64) {
    {
      const float* s = a_src + kt;
      u16x8 cv[4];
#pragma unroll
      for (int q = 0; q < 4; q++) {
        float4 v0 = *(const float4*)(s + q * 8);
        float4 v1 = *(const float4*)(s + q * 8 + 4);
        cv[q][0] = f2bf(v0.x); cv[q][1] = f2bf(v0.y);
        cv[q][2] = f2bf(v0.z); cv[q][3] = f2bf(v0.w);
        cv[q][4] = f2bf(v1.x); cv[q][5] = f2bf(v1.y);
        cv[q][6] = f2bf(v1.z); cv[q][7] = f2bf(v1.w);
      }
#pragma unroll
      for (int q = 0; q < 4; q++)
        *(u16x8*)((char*)As + swz(a_row, (a_half * 32 + q * 8) * 2)) = cv[q];
    }
    {
#pragma unroll
      for (int it = 0; it < 2; it++) {
        const int k0 = (b_kg + 4 * it) * 8;
        u16x8 c0, c1;
#pragma unroll
        for (int j = 0; j < 8; j++) {
          float2 v = *(const float2*)(W + (size_t)(kt + k0 + j) * HDIM + n0 + 2 * b_np);
          c0[j] = f2bf(v.x); c1[j] = f2bf(v.y);
        }
        *(u16x8*)((char*)Bs + swz(2 * b_np,     k0 * 2)) = c0;
        *(u16x8*)((char*)Bs + swz(2 * b_np + 1, k0 * 2)) = c1;
      }
    }
    __syncthreads();
    MFMA_COMPUTE_F((const char*)As, (const char*)Bs)
    __syncthreads();
  }
  int hrow[4][4]; bool valid[4][4];
#pragma unroll
  for (int i = 0; i < 4; i++)
#pragma unroll
    for (int r = 0; r < 4; r++) {
      const int mi = m0 + wm + i * 16 + lgrp * 4 + r;
      valid[i][r] = (mi < cnt);
      const int idx = valid[i][r] ? mi : (cnt - 1);
      hrow[i][r] = h_by_pair ? list[idx] : idx;
    }
#pragma unroll
  for (int j = 0; j < 4; j++) {
    const int col = n0 + wn + j * 16 + lrow;
    const float bias = b1[e * HDIM + col];
#pragma unroll
    for (int i = 0; i < 4; i++)
#pragma unroll
      for (int r = 0; r < 4; r++)
        if (valid[i][r]) {
          float h = acc[i][j][r] + bias;
          h = h > 0.f ? h : 0.f;
          Hb[(size_t)hrow[i][r] * HDIM + col] = f2bf(h);
        }
  }
}

__global__ __launch_bounds__(256) void gemm2_f32_kernel(
    const unsigned short* __restrict__ Hb, const float* __restrict__ w2,
    const float* __restrict__ b2, const float* __restrict__ pair_w,
    const int* __restrict__ counts, const int* __restrict__ lists,
    float* __restrict__ out, int e_base, int h_by_pair)
{
  const int e = e_base + blockIdx.z;
  int cnt = counts[e]; if (cnt > CAP) cnt = CAP;
  const int m0 = blockIdx.y * 128;
  if (m0 >= cnt) return;
  const int n0 = blockIdx.x * 128;
  const int* list = lists + e * CAP;
  const float* W = w2 + (size_t)e * HDIM * CDIM;
  __shared__ __align__(16) unsigned short As[128 * 64];
  __shared__ __align__(16) unsigned short Bs[128 * 64];
  const int t = threadIdx.x;
  const int a_row = t >> 1, a_half = t & 1;
  int a_idx = m0 + a_row; if (a_idx > cnt - 1) a_idx = cnt - 1;
  const unsigned short* a_src =
      Hb + (size_t)(h_by_pair ? list[a_idx] : a_idx) * HDIM + a_half * 32;
  const int b_np = t & 63, b_kg = t >> 6;
  const int wid = t >> 6, lane = t & 63;
  const int wm = (wid >> 1) * 64, wn = (wid & 1) * 64;
  const int lrow = lane & 15, lgrp = lane >> 4;
  f32x4 acc[4][4] = {};
  for (int kt = 0; kt < HDIM; kt += 64) {
    {
      const unsigned short* s = a_src + kt;
#pragma unroll
      for (int q = 0; q < 4; q++) {
        u16x8 v = *(const u16x8*)(s + q * 8);
        *(u16x8*)((char*)As + swz(a_row, (a_half * 32 + q * 8) * 2)) = v;
      }
    }
    {
#pragma unroll
      for (int it = 0; it < 2; it++) {
        const int k0 = (b_kg + 4 * it) * 8;
        u16x8 c0, c1;
#pragma unroll
        for (int j = 0; j < 8; j++) {
          float2 v = *(const float2*)(W + (size_t)(kt + k0 + j) * CDIM + n0 + 2 * b_np);
          c0[j] = f2bf(v.x); c1[j] = f2bf(v.y);
        }
        *(u16x8*)((char*)Bs + swz(2 * b_np,     k0 * 2)) = c0;
        *(u16x8*)((char*)Bs + swz(2 * b_np + 1, k0 * 2)) = c1;
      }
    }
    __syncthreads();
    MFMA_COMPUTE_F((const char*)As, (const char*)Bs)
    __syncthreads();
  }
  float wgt[4][4]; int tok[4][4]; bool valid[4][4];
#pragma unroll
  for (int i = 0; i < 4; i++)
#pragma unroll
    for (int r = 0; r < 4; r++) {
      const int mi = m0 + wm + i * 16 + lgrp * 4 + r;
      valid[i][r] = (mi < cnt);
      const int idx = valid[i][r] ? mi : (cnt - 1);
      const int p = list[idx];
      wgt[i][r] = pair_w[p];
      tok[i][r] = p >> 1;
    }
#pragma unroll
  for (int j = 0; j < 4; j++) {
    const int col = n0 + wn + j * 16 + lrow;
    const float bias = b2[e * CDIM + col];
#pragma unroll
    for (int i = 0; i < 4; i++)
#pragma unroll
      for (int r = 0; r < 4; r++)
        if (valid[i][r])
          atomicAdd(out + (size_t)tok[i][r] * CDIM + col,
                    wgt[i][r] * (acc[i][j][r] + bias));
  }
}

extern "C" void kernel_launch(void* const* d_in, const int* in_sizes, int n_in,
                              void* d_out, int out_size, void* d_ws, size_t ws_size,
                              hipStream_t stream)
{
  const float* x  = (const float*)d_in[0];
  const float* wr = (const float*)d_in[1];
  const float* w1 = (const float*)d_in[2];
  const float* b1 = (const float*)d_in[3];
  const float* w2 = (const float*)d_in[4];
  const float* b2 = (const float*)d_in[5];
  float* out = (float*)d_out;

  const int N = in_sizes[0] / CDIM;  // 8192 tokens

  char* ws = (char*)d_ws;
  int* counts = (int*)ws;
  int* lists  = (int*)(ws + 256);
  float* pw   = (float*)(ws + 256 + NEXP * CAP * 4);
  size_t off = 256 + (size_t)NEXP * CAP * 4 + (size_t)2 * N * 4;
  off = (off + 255) & ~(size_t)255;
  unsigned short* xb = (unsigned short*)(ws + off);
  const size_t xb_sz = (size_t)N * CDIM * 2;
  unsigned short* Hb = (unsigned short*)(ws + off + xb_sz);
  const size_t Hb_sz = (size_t)2 * N * HDIM * 2;
  unsigned short* wb = (unsigned short*)(ws + off + xb_sz + Hb_sz);
  const size_t wb_sz = (size_t)NEXP * CDIM * HDIM * 2;

  const size_t need_new = off + xb_sz + Hb_sz + wb_sz;     // ~285 MB
  const size_t need_old = off + Hb_sz;                     // ~134.5 MB

  hipMemsetAsync(d_ws, 0, 64, stream);
  hipMemsetAsync(d_out, 0, (size_t)out_size * 4, stream);

  router_kernel<<<N, 64, 0, stream>>>(x, wr, pw, counts, lists);

  if (ws_size >= need_new) {
    cvt_x_kernel<<<(N * CDIM / 8 + 255) / 256, 256, 0, stream>>>(
        x, xb, N * CDIM / 8);
    transpose_cvt_kernel<<<dim3(HDIM / 64, CDIM / 64, NEXP), 256, 0, stream>>>(
        w1, wb, CDIM, HDIM);
    gemm1_8p_kernel<<<dim3(HDIM / BNG, CAP / BMG, NEXP), 512, 0, stream>>>(
        xb, wb, b1, counts, lists, Hb);
    transpose_cvt_kernel<<<dim3(CDIM / 64, HDIM / 64, NEXP), 256, 0, stream>>>(
        w2, wb, HDIM, CDIM);
    gemm2_8p_kernel<<<dim3(CDIM / BNG, CAP / BMG, NEXP * KS2), 512, 0, stream>>>(
        Hb, wb, b2, pw, counts, lists, out);
  } else if (ws_size >= need_old) {
    unsigned short* Hb0 = (unsigned short*)(ws + off);
    gemm1_f32_kernel<<<dim3(HDIM / 128, CAP / 128, NEXP), 256, 0, stream>>>(
        x, w1, b1, counts, lists, Hb0, 0, 1);
    gemm2_f32_kernel<<<dim3(CDIM / 128, CAP / 128, NEXP), 256, 0, stream>>>(
        Hb0, w2, b2, pw, counts, lists, out, 0, 1);
  }
}

// Round 8
// 876.747 us; speedup vs baseline: 1.0821x; 1.0821x over previous
//
#include <hip/hip_runtime.h>
#include <hip/hip_bf16.h>

// DynamicRouterMoE: N=8192 tokens, C=1024, Hdim=4096, E=16, top-2.
// R8: kill the fixed passes. B-operand is staged DIRECTLY from native fp32
//     weights (transpose realized in the reg->LDS write pattern, T14), so
//     both transpose_cvt passes and the wb buffer are gone. x->bf16 cvt is
//     fused into the router. GEMM compute skeleton identical to R7.

typedef __attribute__((ext_vector_type(4))) float f32x4;
typedef __attribute__((ext_vector_type(8))) __bf16 bf16x8;
typedef __attribute__((ext_vector_type(8))) unsigned short u16x8;

#define NEXP 16
#define CAP  2048
#define CDIM 1024
#define HDIM 4096
#define KS2 2            // split-K factor for gemm2
#define BMG 256          // GEMM tile M
#define BNG 256          // GEMM tile N
#define SLOT 8192        // elems per LDS slot: 256 rows x 32 k

__device__ __forceinline__ unsigned short f2bf(float f) {
  return __builtin_bit_cast(unsigned short, (__bf16)f);
}

// Bijective XCD swizzle (requires nwg % 8 == 0; true for all GEMM grids).
__device__ __forceinline__ void xcd_remap(int& bx, int& by, int& bz) {
  const int gx = gridDim.x, gy = gridDim.y;
  const int nwg = gx * gy * gridDim.z;
  int flat = blockIdx.x + gx * (blockIdx.y + gy * blockIdx.z);
  flat = (flat & 7) * (nwg >> 3) + (flat >> 3);
  bx = flat % gx;
  const int t = flat / gx;
  by = t % gy;
  bz = t / gy;
}

// ------- router: logits(fp64) -> top2 -> softmax -> lists; fused x->bf16 ----
__global__ __launch_bounds__(64) void router_kernel(
    const float* __restrict__ x, const float* __restrict__ wr,
    float* __restrict__ pair_w, int* __restrict__ counts,
    int* __restrict__ lists, unsigned short* __restrict__ xb)
{
  const int n = blockIdx.x;
  const int l = threadIdx.x;
  const float* xrow = x + (size_t)n * CDIM;
  unsigned short* xbrow = xb + (size_t)n * CDIM;
  double acc[NEXP];
#pragma unroll
  for (int e = 0; e < NEXP; e++) acc[e] = 0.0;
  for (int it = 0; it < CDIM / 64; it++) {
    const int c = l + it * 64;
    const float xf = xrow[c];
    xbrow[c] = f2bf(xf);                 // fused bf16 conversion
    const double xv = (double)xf;
    const float* w = wr + c * NEXP;
#pragma unroll
    for (int e = 0; e < NEXP; e++) acc[e] += xv * (double)w[e];
  }
#pragma unroll
  for (int e = 0; e < NEXP; e++) {
    double v = acc[e];
    for (int off = 32; off > 0; off >>= 1) v += __shfl_xor(v, off, 64);
    acc[e] = v;
  }
  if (l == 0) {
    int e0 = 0; double b0 = acc[0];
    for (int e = 1; e < NEXP; e++) if (acc[e] > b0) { b0 = acc[e]; e0 = e; }
    int e1 = -1; double b1v = -1e300;
    for (int e = 0; e < NEXP; e++) {
      if (e == e0) continue;
      if (acc[e] > b1v) { b1v = acc[e]; e1 = e; }
    }
    const double d = exp(b1v - b0);
    pair_w[2 * n]     = (float)(1.0 / (1.0 + d));
    pair_w[2 * n + 1] = (float)(d / (1.0 + d));
    int p0 = atomicAdd(&counts[e0], 1);
    if (p0 < CAP) lists[e0 * CAP + p0] = 2 * n;
    int p1 = atomicAdd(&counts[e1], 1);
    if (p1 < CAP) lists[e1 * CAP + p1] = 2 * n + 1;
  }
}

// ========= 8-wave 256x256 reg-staged GEMM bodies ============================
// LDS: A slots [par][h][256 rows][32 k] then B slots (8 x 16KB = 128KB).
// Stored quad q' holds global quad g = q' ^ ((row>>1)&3)  (R6-verified).
// A: bf16 source, 4 x 16B loads + 4 swizzled ds_write_b128 per tile.
// B: native fp32 [k][n] source. Per thread: one n (brow=t&255), k-half
//    bh=t>>8, 4 octet-units x 8 k-strided dword loads (wave-coalesced over
//    n), cvt to bf16 in reg, 4 swizzled ds_write_b128 in [n][k] order.
// Loop: 1 barrier per K-tile; regs lead consumption by 1 tile; loads for
// tile t+2 issued at tile t (compiler-counted vmcnt, never drained mid-loop).

#define LOADA(kbyte)                                                           \
  do {                                                                         \
    rA0 = *(const u16x8*)(ag0 + (kbyte));                                      \
    rA1 = *(const u16x8*)(ag1 + (kbyte));                                      \
    rA2 = *(const u16x8*)(ag0 + (kbyte) + 64);                                 \
    rA3 = *(const u16x8*)(ag1 + (kbyte) + 64);                                 \
  } while (0)

#define DSWA(parx)                                                             \
  do {                                                                         \
    unsigned short* S0_ = &lds[((parx) * 2 + 0) * SLOT];                       \
    unsigned short* S1_ = &lds[((parx) * 2 + 1) * SLOT];                       \
    *(u16x8*)(S0_ + sw0) = rA0;                                                \
    *(u16x8*)(S0_ + sw1) = rA1;                                                \
    *(u16x8*)(S1_ + sw0) = rA2;                                                \
    *(u16x8*)(S1_ + sw1) = rA3;                                                \
  } while (0)

#define LOADB(ktv)                                                             \
  do {                                                                         \
    _Pragma("unroll")                                                          \
    for (int u = 0; u < 4; u++)                                                \
      _Pragma("unroll")                                                        \
      for (int j = 0; j < 8; j++)                                              \
        rB[u][j] = bgu[u][(size_t)((ktv) + j) * BNN];                          \
  } while (0)

#define DSWB(parx)                                                             \
  do {                                                                         \
    unsigned short* SB_ = &lds[4 * SLOT + ((parx) * 2 + bh) * SLOT];           \
    _Pragma("unroll")                                                          \
    for (int u = 0; u < 4; u++) {                                              \
      u16x8 v_;                                                                \
      _Pragma("unroll")                                                        \
      for (int j = 0; j < 8; j++) v_[j] = f2bf(rB[u][j]);                      \
      *(u16x8*)(SB_ + brow * 32 + (u ^ bqx) * 8) = v_;                         \
    }                                                                          \
  } while (0)

#define COMPUTE(parx, hx)                                                      \
  do {                                                                         \
    const unsigned short* As_ = &lds[((parx) * 2 + (hx)) * SLOT];              \
    const unsigned short* Bs_ = &lds[4 * SLOT + ((parx) * 2 + (hx)) * SLOT];   \
    bf16x8 af[8], bfv[4];                                                      \
    _Pragma("unroll")                                                          \
    for (int mf = 0; mf < 8; mf++)                                             \
      af[mf] = *(const bf16x8*)(As_ + (wr * 128 + mf * 16 + lrow) * 32 + qsw); \
    _Pragma("unroll")                                                          \
    for (int nf = 0; nf < 4; nf++)                                             \
      bfv[nf] = *(const bf16x8*)(Bs_ + (wc * 64 + nf * 16 + lrow) * 32 + qsw); \
    __builtin_amdgcn_s_setprio(1);                                             \
    _Pragma("unroll")                                                          \
    for (int mf = 0; mf < 8; mf++)                                             \
      _Pragma("unroll")                                                        \
      for (int nf = 0; nf < 4; nf++)                                           \
        acc[mf][nf] = __builtin_amdgcn_mfma_f32_16x16x32_bf16(                 \
            af[mf], bfv[nf], acc[mf][nf], 0, 0, 0);                            \
    __builtin_amdgcn_s_setprio(0);                                             \
  } while (0)

#define SBAR asm volatile("s_barrier" ::: "memory")

#define GEMM_MAIN_LOOP(NT)                                                     \
  u16x8 rA0, rA1, rA2, rA3; float rB[4][8];                                    \
  LOADA(0); LOADB(0);                                                          \
  DSWA(0); DSWB(0);                                                            \
  LOADA(128); LOADB(64);                                                       \
  asm volatile("s_waitcnt lgkmcnt(0)" ::: "memory");                           \
  for (int tt = 0; tt < (NT); ++tt) {                                          \
    const int par = tt & 1;                                                    \
    SBAR;                                                                      \
    if (tt + 1 < (NT)) { DSWA(par ^ 1); DSWB(par ^ 1); }                       \
    if (tt + 2 < (NT)) { LOADA((tt + 2) * 128); LOADB((tt + 2) * 64); }        \
    COMPUTE(par, 0);                                                           \
    COMPUTE(par, 1);                                                           \
  }

// ---------------- GEMM1: H[pair] = relu(xb[token] @ w1[e] + b1[e]) ----------
// B source: w1[e] native fp32 [C=k][H=n], BNN = HDIM.
__global__ __launch_bounds__(512, 2) void gemm1_8p_kernel(
    const unsigned short* __restrict__ xb, const float* __restrict__ w1f,
    const float* __restrict__ b1, const int* __restrict__ counts,
    const int* __restrict__ lists, unsigned short* __restrict__ Hb)
{
  int bx, by, bz;
  xcd_remap(bx, by, bz);
  const int e = bz;
  int cnt = counts[e]; if (cnt > CAP) cnt = CAP;
  const int m0 = by * BMG;
  if (m0 >= cnt) return;
  const int n0 = bx * BNG;
  const int* list = lists + e * CAP;
  const float* Wf = w1f + (size_t)e * CDIM * HDIM;
  const int BNN = HDIM;

  __shared__ __align__(16) unsigned short lds[8 * SLOT];  // 128 KB

  const int t = threadIdx.x, w = t >> 6, lane = t & 63;
  const int wr = w >> 2, wc = w & 3;          // 2M x 4N waves, each 128x64
  const int lrow = lane & 15, lgrp = lane >> 4;
  const int qsw = (lgrp ^ ((lrow >> 1) & 3)) * 8;

  // A staging (bf16, gathered rows)
  const int sr0 = w * 16 + (lane >> 2), sr1 = 128 + sr0;
  const int wq = ((lane & 3) ^ ((lane >> 3) & 3)) * 8;
  const int sw0 = sr0 * 32 + wq, sw1 = sr1 * 32 + wq;
  int ai0 = m0 + sr0; if (ai0 > cnt - 1) ai0 = cnt - 1;
  int ai1 = m0 + sr1; if (ai1 > cnt - 1) ai1 = cnt - 1;
  const char* ag0 = (const char*)(xb + (size_t)(list[ai0] >> 1) * CDIM) + (lane & 3) * 16;
  const char* ag1 = (const char*)(xb + (size_t)(list[ai1] >> 1) * CDIM) + (lane & 3) * 16;

  // B staging (fp32 [k][n] -> bf16 [n][k])
  const int brow = t & 255, bh = t >> 8, bqx = (brow >> 1) & 3;
  const float* bgu[4];
#pragma unroll
  for (int u = 0; u < 4; u++)
    bgu[u] = Wf + (size_t)(bh * 32 + u * 8) * BNN + n0 + brow;

  f32x4 acc[8][4] = {};

  GEMM_MAIN_LOOP(CDIM / 64)

  // epilogue: +b1, relu, bf16 scatter to Hb rows = pair ids
  int hrow[8][4]; bool valid[8][4];
#pragma unroll
  for (int mf = 0; mf < 8; mf++)
#pragma unroll
    for (int rr = 0; rr < 4; rr++) {
      const int mi = m0 + wr * 128 + mf * 16 + lgrp * 4 + rr;
      valid[mf][rr] = (mi < cnt);
      hrow[mf][rr] = list[valid[mf][rr] ? mi : (cnt - 1)];
    }
#pragma unroll
  for (int nf = 0; nf < 4; nf++) {
    const int col = n0 + wc * 64 + nf * 16 + lrow;
    const float bias = b1[e * HDIM + col];
#pragma unroll
    for (int mf = 0; mf < 8; mf++)
#pragma unroll
      for (int rr = 0; rr < 4; rr++)
        if (valid[mf][rr]) {
          float h = acc[mf][nf][rr] + bias;
          h = h > 0.f ? h : 0.f;
          Hb[(size_t)hrow[mf][rr] * HDIM + col] = f2bf(h);
        }
  }
}

// ---------------- GEMM2: out[token] += w_pair*(Hb[pair] @ w2[e] + b2) -------
// B source: w2[e] native fp32 [H=k][C=n], BNN = CDIM. Split-K x2.
__global__ __launch_bounds__(512, 2) void gemm2_8p_kernel(
    const unsigned short* __restrict__ Hb, const float* __restrict__ w2f,
    const float* __restrict__ b2, const float* __restrict__ pair_w,
    const int* __restrict__ counts, const int* __restrict__ lists,
    float* __restrict__ out)
{
  int bx, by, bz;
  xcd_remap(bx, by, bz);
  const int e = bz / KS2, ks = bz % KS2;
  int cnt = counts[e]; if (cnt > CAP) cnt = CAP;
  const int m0 = by * BMG;
  if (m0 >= cnt) return;
  const int n0 = bx * BNG;
  const int* list = lists + e * CAP;
  const float* Wf = w2f + (size_t)e * HDIM * CDIM;
  const int BNN = CDIM;
  const int kbeg = ks * (HDIM / KS2);

  __shared__ __align__(16) unsigned short lds[8 * SLOT];  // 128 KB

  const int t = threadIdx.x, w = t >> 6, lane = t & 63;
  const int wr = w >> 2, wc = w & 3;
  const int lrow = lane & 15, lgrp = lane >> 4;
  const int qsw = (lgrp ^ ((lrow >> 1) & 3)) * 8;

  const int sr0 = w * 16 + (lane >> 2), sr1 = 128 + sr0;
  const int wq = ((lane & 3) ^ ((lane >> 3) & 3)) * 8;
  const int sw0 = sr0 * 32 + wq, sw1 = sr1 * 32 + wq;
  int ai0 = m0 + sr0; if (ai0 > cnt - 1) ai0 = cnt - 1;
  int ai1 = m0 + sr1; if (ai1 > cnt - 1) ai1 = cnt - 1;
  const char* ag0 = (const char*)(Hb + (size_t)list[ai0] * HDIM + kbeg) + (lane & 3) * 16;
  const char* ag1 = (const char*)(Hb + (size_t)list[ai1] * HDIM + kbeg) + (lane & 3) * 16;

  const int brow = t & 255, bh = t >> 8, bqx = (brow >> 1) & 3;
  const float* bgu[4];
#pragma unroll
  for (int u = 0; u < 4; u++)
    bgu[u] = Wf + (size_t)(kbeg + bh * 32 + u * 8) * BNN + n0 + brow;

  f32x4 acc[8][4] = {};

  GEMM_MAIN_LOOP((HDIM / KS2) / 64)

  // epilogue: +b2 (ks==0 only), scale by routing weight, atomic accumulate.
  float wgt[8][4]; int tok[8][4]; bool valid[8][4];
#pragma unroll
  for (int mf = 0; mf < 8; mf++)
#pragma unroll
    for (int rr = 0; rr < 4; rr++) {
      const int mi = m0 + wr * 128 + mf * 16 + lgrp * 4 + rr;
      valid[mf][rr] = (mi < cnt);
      const int p = list[valid[mf][rr] ? mi : (cnt - 1)];
      wgt[mf][rr] = pair_w[p];
      tok[mf][rr] = p >> 1;
    }
#pragma unroll
  for (int nf = 0; nf < 4; nf++) {
    const int col = n0 + wc * 64 + nf * 16 + lrow;
    const float bias = (ks == 0) ? b2[e * CDIM + col] : 0.f;
#pragma unroll
    for (int mf = 0; mf < 8; mf++)
#pragma unroll
      for (int rr = 0; rr < 4; rr++)
        if (valid[mf][rr])
          atomicAdd(out + (size_t)tok[mf][rr] * CDIM + col,
                    wgt[mf][rr] * (acc[mf][nf][rr] + bias));
  }
}

// ================= fallback kernels (fp32 inputs, reg-staged, 128²) =========
__device__ __forceinline__ int swz(int row, int b) {
  return row * 128 + (b ^ (((row >> 1) & 7) << 4));
}

#define MFMA_COMPUTE_F(Abase, Bbase)                                           \
  _Pragma("unroll")                                                            \
  for (int kk = 0; kk < 2; kk++) {                                             \
    bf16x8 af[4], bfr[4];                                                      \
    const int kb = (kk * 32 + lgrp * 8) * 2;                                   \
    _Pragma("unroll")                                                          \
    for (int i = 0; i < 4; i++)                                                \
      af[i] = *(const bf16x8*)((Abase) + swz(wm + i * 16 + lrow, kb));         \
    _Pragma("unroll")                                                          \
    for (int j = 0; j < 4; j++)                                                \
      bfr[j] = *(const bf16x8*)((Bbase) + swz(wn + j * 16 + lrow, kb));        \
    _Pragma("unroll")                                                          \
    for (int i = 0; i < 4; i++)                                                \
      _Pragma("unroll")                                                        \
      for (int j = 0; j < 4; j++)                                              \
        acc[i][j] = __builtin_amdgcn_mfma_f32_16x16x32_bf16(                   \
            af[i], bfr[j], acc[i][j], 0, 0, 0);                                \
  }

__global__ __launch_bounds__(256) void gemm1_f32_kernel(
    const float* __restrict__ x, const float* __restrict__ w1,
    const float* __restrict__ b1, const int* __restrict__ counts,
    const int* __restrict__ lists, unsigned short* __restrict__ Hb,
    int e_base, int h_by_pair)
{
  const int e = e_base + blockIdx.z;
  int cnt = counts[e]; if (cnt > CAP) cnt = CAP;
  const int m0 = blockIdx.y * 128;
  if (m0 >= cnt) return;
  const int n0 = blockIdx.x * 128;
  const int* list = lists + e * CAP;
  const float* W = w1 + (size_t)e * CDIM * HDIM;
  __shared__ __align__(16) unsigned short As[128 * 64];
  __shared__ __align__(16) unsigned short Bs[128 * 64];
  const int t = threadIdx.x;
  const int a_row = t >> 1, a_half = t & 1;
  int a_idx = m0 + a_row; if (a_idx > cnt - 1) a_idx = cnt - 1;
  const float* a_src = x + (size_t)(list[a_idx] >> 1) * CDIM + a_half * 32;
  const int b_np = t & 63, b_kg = t >> 6;
  const int wid = t >> 6, lane = t & 63;
  const int wm = (wid >> 1) * 64, wn = (wid & 1) * 64;
  const int lrow = lane & 15, lgrp = lane >> 4;
  f32x4 acc[4][4] = {};
  for (int kt = 0; kt < CDIM; kt += 64) {
    {
      const float* s = a_src + kt;
      u16x8 cv[4];
#pragma unroll
      for (int q = 0; q < 4; q++) {
        float4 v0 = *(const float4*)(s + q * 8);
        float4 v1 = *(const float4*)(s + q * 8 + 4);
        cv[q][0] = f2bf(v0.x); cv[q][1] = f2bf(v0.y);
        cv[q][2] = f2bf(v0.z); cv[q][3] = f2bf(v0.w);
        cv[q][4] = f2bf(v1.x); cv[q][5] = f2bf(v1.y);
        cv[q][6] = f2bf(v1.z); cv[q][7] = f2bf(v1.w);
      }
#pragma unroll
      for (int q = 0; q < 4; q++)
        *(u16x8*)((char*)As + swz(a_row, (a_half * 32 + q * 8) * 2)) = cv[q];
    }
    {
#pragma unroll
      for (int it = 0; it < 2; it++) {
        const int k0 = (b_kg + 4 * it) * 8;
        u16x8 c0, c1;
#pragma unroll
        for (int j = 0; j < 8; j++) {
          float2 v = *(const float2*)(W + (size_t)(kt + k0 + j) * HDIM + n0 + 2 * b_np);
          c0[j] = f2bf(v.x); c1[j] = f2bf(v.y);
        }
        *(u16x8*)((char*)Bs + swz(2 * b_np,     k0 * 2)) = c0;
        *(u16x8*)((char*)Bs + swz(2 * b_np + 1, k0 * 2)) = c1;
      }
    }
    __syncthreads();
    MFMA_COMPUTE_F((const char*)As, (const char*)Bs)
    __syncthreads();
  }
  int hrow[4][4]; bool valid[4][4];
#pragma unroll
  for (int i = 0; i < 4; i++)
#pragma unroll
    for (int r = 0; r < 4; r++) {
      const int mi = m0 + wm + i * 16 + lgrp * 4 + r;
      valid[i][r] = (mi < cnt);
      const int idx = valid[i][r] ? mi : (cnt - 1);
      hrow[i][r] = h_by_pair ? list[idx] : idx;
    }
#pragma unroll
  for (int j = 0; j < 4; j++) {
    const int col = n0 + wn + j * 16 + lrow;
    const float bias = b1[e * HDIM + col];
#pragma unroll
    for (int i = 0; i < 4; i++)
#pragma unroll
      for (int r = 0; r < 4; r++)
        if (valid[i][r]) {
          float h = acc[i][j][r] + bias;
          h = h > 0.f ? h : 0.f;
          Hb[(size_t)hrow[i][r] * HDIM + col] = f2bf(h);
        }
  }
}

__global__ __launch_bounds__(256) void gemm2_f32_kernel(
    const unsigned short* __restrict__ Hb, const float* __restrict__ w2,
    const float* __restrict__ b2, const float* __restrict__ pair_w,
    const int* __restrict__ counts, const int* __restrict__ lists,
    float* __restrict__ out, int e_base, int h_by_pair)
{
  const int e = e_base + blockIdx.z;
  int cnt = counts[e]; if (cnt > CAP) cnt = CAP;
  const int m0 = blockIdx.y * 128;
  if (m0 >= cnt) return;
  const int n0 = blockIdx.x * 128;
  const int* list = lists + e * CAP;
  const float* W = w2 + (size_t)e * HDIM * CDIM;
  __shared__ __align__(16) unsigned short As[128 * 64];
  __shared__ __align__(16) unsigned short Bs[128 * 64];
  const int t = threadIdx.x;
  const int a_row = t >> 1, a_half = t & 1;
  int a_idx = m0 + a_row; if (a_idx > cnt - 1) a_idx = cnt - 1;
  const unsigned short* a_src =
      Hb + (size_t)(h_by_pair ? list[a_idx] : a_idx) * HDIM + a_half * 32;
  const int b_np = t & 63, b_kg = t >> 6;
  const int wid = t >> 6, lane = t & 63;
  const int wm = (wid >> 1) * 64, wn = (wid & 1) * 64;
  const int lrow = lane & 15, lgrp = lane >> 4;
  f32x4 acc[4][4] = {};
  for (int kt = 0; kt < HDIM; kt += 64) {
    {
      const unsigned short* s = a_src + kt;
#pragma unroll
      for (int q = 0; q < 4; q++) {
        u16x8 v = *(const u16x8*)(s + q * 8);
        *(u16x8*)((char*)As + swz(a_row, (a_half * 32 + q * 8) * 2)) = v;
      }
    }
    {
#pragma unroll
      for (int it = 0; it < 2; it++) {
        const int k0 = (b_kg + 4 * it) * 8;
        u16x8 c0, c1;
#pragma unroll
        for (int j = 0; j < 8; j++) {
          float2 v = *(const float2*)(W + (size_t)(kt + k0 + j) * CDIM + n0 + 2 * b_np);
          c0[j] = f2bf(v.x); c1[j] = f2bf(v.y);
        }
        *(u16x8*)((char*)Bs + swz(2 * b_np,     k0 * 2)) = c0;
        *(u16x8*)((char*)Bs + swz(2 * b_np + 1, k0 * 2)) = c1;
      }
    }
    __syncthreads();
    MFMA_COMPUTE_F((const char*)As, (const char*)Bs)
    __syncthreads();
  }
  float wgt[4][4]; int tok[4][4]; bool valid[4][4];
#pragma unroll
  for (int i = 0; i < 4; i++)
#pragma unroll
    for (int r = 0; r < 4; r++) {
      const int mi = m0 + wm + i * 16 + lgrp * 4 + r;
      valid[i][r] = (mi < cnt);
      const int idx = valid[i][r] ? mi : (cnt - 1);
      const int p = list[idx];
      wgt[i][r] = pair_w[p];
      tok[i][r] = p >> 1;
    }
#pragma unroll
  for (int j = 0; j < 4; j++) {
    const int col = n0 + wn + j * 16 + lrow;
    const float bias = b2[e * CDIM + col];
#pragma unroll
    for (int i = 0; i < 4; i++)
#pragma unroll
      for (int r = 0; r < 4; r++)
        if (valid[i][r])
          atomicAdd(out + (size_t)tok[i][r] * CDIM + col,
                    wgt[i][r] * (acc[i][j][r] + bias));
  }
}

extern "C" void kernel_launch(void* const* d_in, const int* in_sizes, int n_in,
                              void* d_out, int out_size, void* d_ws, size_t ws_size,
                              hipStream_t stream)
{
  const float* x  = (const float*)d_in[0];
  const float* wr = (const float*)d_in[1];
  const float* w1 = (const float*)d_in[2];
  const float* b1 = (const float*)d_in[3];
  const float* w2 = (const float*)d_in[4];
  const float* b2 = (const float*)d_in[5];
  float* out = (float*)d_out;

  const int N = in_sizes[0] / CDIM;  // 8192 tokens

  char* ws = (char*)d_ws;
  int* counts = (int*)ws;
  int* lists  = (int*)(ws + 256);
  float* pw   = (float*)(ws + 256 + NEXP * CAP * 4);
  size_t off = 256 + (size_t)NEXP * CAP * 4 + (size_t)2 * N * 4;
  off = (off + 255) & ~(size_t)255;
  unsigned short* xb = (unsigned short*)(ws + off);
  const size_t xb_sz = (size_t)N * CDIM * 2;
  unsigned short* Hb = (unsigned short*)(ws + off + xb_sz);
  const size_t Hb_sz = (size_t)2 * N * HDIM * 2;

  const size_t need_new = off + xb_sz + Hb_sz;             // ~151 MB
  const size_t need_old = off + Hb_sz;                     // ~134.5 MB

  hipMemsetAsync(d_ws, 0, 64, stream);
  hipMemsetAsync(d_out, 0, (size_t)out_size * 4, stream);

  if (ws_size >= need_new) {
    router_kernel<<<N, 64, 0, stream>>>(x, wr, pw, counts, lists, xb);
    gemm1_8p_kernel<<<dim3(HDIM / BNG, CAP / BMG, NEXP), 512, 0, stream>>>(
        xb, w1, b1, counts, lists, Hb);
    gemm2_8p_kernel<<<dim3(CDIM / BNG, CAP / BMG, NEXP * KS2), 512, 0, stream>>>(
        Hb, w2, b2, pw, counts, lists, out);
  } else if (ws_size >= need_old) {
    // fallback: router still needs an xb target; reuse Hb region transiently
    // (gemm1_f32 reads x directly and overwrites it afterwards).
    unsigned short* Hb0 = (unsigned short*)(ws + off);
    router_kernel<<<N, 64, 0, stream>>>(x, wr, pw, counts, lists, Hb0);
    gemm1_f32_kernel<<<dim3(HDIM / 128, CAP / 128, NEXP), 256, 0, stream>>>(
        x, w1, b1, counts, lists, Hb0, 0, 1);
    gemm2_f32_kernel<<<dim3(CDIM / 128, CAP / 128, NEXP), 256, 0, stream>>>(
        Hb0, w2, b2, pw, counts, lists, out, 0, 1);
  }
}